// Round 9
// baseline (545.186 us; speedup 1.0000x reference)
//
#include <hip/hip_runtime.h>
#include <hip/hip_bf16.h>

// B=4, C=256, N=HW=4096, Dqk=32.
// Round 17: R16 falsified the byte-law (bytes -32%, time 0%); attn is pinned
// at ~1960 cyc/body across SIX structural variants (wave count, barriers,
// pipeline depth, byte totals) -> per-wave issue/latency serialization this
// structure cannot escape; attn ~52us is its empirical floor. The dominant
// remaining cost is REST = total - attn ~ 84us, constant for 9 rounds and
// immune to two different qkv kernels; static qkv+wpack <= 12us, so ~60-70us
// is inter-kernel launch/serialization overhead. Only source-level probe:
// FUSE qkv+attn into one kernel. Grid 256 x 1024 (1 block/CU; lb(1024,8)
// caps VGPR 64 -> 2-block/CU capacity -> spin barrier cannot deadlock).
// Phase 1 = R14 qkv for 2 tiles/block; device-atomic grid barrier
// (threadfence + atomicAdd, counter zeroed by wpack each iter, poison-safe);
// Phase 2 = exact R15 attn (best measured, VGPR 56). LDS unioned.
// Carried: wave-specialized attn, K-dedup, conflict-free 16B-slot P layout,
// x2 unroll, SGPR-base addressing, &63 wrap prefetch, packed-Vp, S^T trick,
// LDS-only barrier, XCD swizzle, packed-W, no-max softmax.

#define N_PIX 4096
#define DQK   32
#define CCH   256
#define LOG2E 1.44269504088896f

typedef __attribute__((ext_vector_type(8))) _Float16 f16x8;
typedef __attribute__((ext_vector_type(4))) _Float16 f16x4;
typedef __attribute__((ext_vector_type(2))) _Float16 f16x2;
typedef __attribute__((ext_vector_type(8))) short    bf16x8;
typedef __attribute__((ext_vector_type(4))) short    bf16x4;
typedef __attribute__((ext_vector_type(4))) float    f32x4;

// LDS-only block barrier: waits lgkmcnt(0) but leaves vmcnt untouched.
__device__ inline void barrier_lds() {
    asm volatile("" ::: "memory");
    __builtin_amdgcn_s_waitcnt(0xc07f);   // vmcnt=63, expcnt=7, lgkmcnt=0
    __builtin_amdgcn_s_barrier();
    asm volatile("" ::: "memory");
}

// pack two f32 -> two bf16 in one instruction (RNE)
__device__ inline unsigned cvt_pk_bf16(float lo, float hi) {
    unsigned r;
    asm("v_cvt_pk_bf16_f32 %0, %1, %2" : "=v"(r) : "v"(lo), "v"(hi));
    return r;
}

// ---------------------------------------------------------------------------
// Kernel 0: pack Wq|Wk|Wv -> f16 A-fragments (LOG2E folded into Wq).
// Block 0 also zeroes the grid-barrier counter (re-poison-safe: runs every
// iteration, stream-ordered before the fused kernel).
// ---------------------------------------------------------------------------
__global__ __launch_bounds__(256) void wpack_kernel(
    const float* __restrict__ Wq, const float* __restrict__ Wk,
    const float* __restrict__ Wv, _Float16* __restrict__ Wp,
    unsigned* __restrict__ cnt)
{
    if (blockIdx.x == 0 && threadIdx.x == 0) atomicExch(cnt, 0u);

    const int tid   = threadIdx.x;
    const int wflat = blockIdx.x * 4 + (tid >> 6);   // 0..159
    const int lane  = tid & 63;
    const int L15   = lane & 15;
    const int quad  = lane >> 4;
    const int mt    = wflat >> 3;
    const int ks    = wflat & 7;
    const int m0    = mt * 16;

    const float* Wsrc; int row; float scale = 1.f;
    if (m0 < 32)      { Wsrc = Wq; row = m0 + L15;      scale = LOG2E; }
    else if (m0 < 64) { Wsrc = Wk; row = m0 - 32 + L15; }
    else              { Wsrc = Wv; row = m0 - 64 + L15; }

    const float* p = Wsrc + (size_t)row * 256 + ks * 32 + quad * 8;
    f16x8 h;
    #pragma unroll
    for (int j = 0; j < 8; ++j) h[j] = (_Float16)(p[j] * scale);
    *(f16x8*)(Wp + ((size_t)wflat * 64 + lane) * 8) = h;
}

// ---------------------------------------------------------------------------
// Fused kernel: Phase 1 = QKV (2 x 32-px tiles per block), grid barrier,
// Phase 2 = attention (R15 structure). Grid 256 (XCD-swizzled), 1024 thr.
// ---------------------------------------------------------------------------

#define PV_BODY(J, VR)                                                            \
  {                                                                               \
    const int buf_ = (J) & 1;                                                     \
    _Pragma("unroll")                                                             \
    for (int qq_ = 0; qq_ < 4; ++qq_) {                                           \
      _Pragma("unroll")                                                           \
      for (int kk_ = 0; kk_ < 2; ++kk_) {                                         \
        const bf16x8 ap_ = *(const bf16x8*)(&Ps[buf_][qq_ * 2 + kk_][quad][L15][0]); \
        oacc[qq_][0] = __builtin_amdgcn_mfma_f32_16x16x32_bf16(                   \
            ap_, VR[kk_][0], oacc[qq_][0], 0, 0, 0);                              \
        oacc[qq_][1] = __builtin_amdgcn_mfma_f32_16x16x32_bf16(                   \
            ap_, VR[kk_][1], oacc[qq_][1], 0, 0, 0);                              \
      }                                                                           \
    }                                                                             \
    const __hip_bfloat16* vt_ = vb + (size_t)(((J) + 2) & 63) * 16384;            \
    _Pragma("unroll")                                                             \
    for (int kk_ = 0; kk_ < 2; ++kk_)                                             \
      _Pragma("unroll")                                                           \
      for (int cf_ = 0; cf_ < 2; ++cf_)                                           \
        VR[kk_][cf_] = *(const bf16x8*)(vt_ + voff0 + kk_ * 8192 + cf_ * 512);    \
  }

// S body J (R15 K-dedup): computes S(J+1) for tiles (2h,skt),(2h+1,skt) from
// KR = K(J+1), writes P(J+1) to buf (J&1)^1, prefetches K(J+3) into KR.
#define S_BODY(J, KR, DO_S)                                                       \
  {                                                                               \
    if (DO_S) {                                                                   \
      const int bufw_ = ((J) & 1) ^ 1;                                            \
      const f32x4 s0_ = __builtin_amdgcn_mfma_f32_16x16x32_f16(KR, aq0, fz, 0, 0, 0); \
      const f32x4 s1_ = __builtin_amdgcn_mfma_f32_16x16x32_f16(KR, aq1, fz, 0, 0, 0); \
      const _Float16* kp_ = kbp + (size_t)(((J) + 3) & 63) * (64 * DQK);          \
      KR = *(const f16x8*)(kp_ + koff);                                           \
      const float a0_ = exp2f(s0_[0]), a1_ = exp2f(s0_[1]);                       \
      const float a2_ = exp2f(s0_[2]), a3_ = exp2f(s0_[3]);                       \
      psum0 += (a0_ + a1_) + (a2_ + a3_);                                         \
      uint2 w0_; w0_.x = cvt_pk_bf16(a0_, a1_); w0_.y = cvt_pk_bf16(a2_, a3_);    \
      *(uint2*)(&Ps[bufw_][g0][s8][L15][e4]) = w0_;                               \
      const float b0_ = exp2f(s1_[0]), b1_ = exp2f(s1_[1]);                       \
      const float b2_ = exp2f(s1_[2]), b3_ = exp2f(s1_[3]);                       \
      psum1 += (b0_ + b1_) + (b2_ + b3_);                                         \
      uint2 w1_; w1_.x = cvt_pk_bf16(b0_, b1_); w1_.y = cvt_pk_bf16(b2_, b3_);    \
      *(uint2*)(&Ps[bufw_][g1][s8][L15][e4]) = w1_;                               \
    }                                                                             \
  }

__global__ __launch_bounds__(1024, 8) void fused_kernel(
    const float* __restrict__ x, const _Float16* __restrict__ Wp,
    const float* __restrict__ bq, const float* __restrict__ bk,
    const float* __restrict__ bv,
    _Float16* __restrict__ qo, _Float16* __restrict__ ko,
    __hip_bfloat16* __restrict__ vpk,
    float* __restrict__ out, unsigned* __restrict__ cnt)
{
    __shared__ alignas(16) unsigned char smem[20480];

    const int idx  = blockIdx.x;
    const int tid  = threadIdx.x;
    const int wid  = tid >> 6;
    const int lane = tid & 63;
    const int L15  = lane & 15;
    const int quad = lane >> 4;
    const f32x4 fz = {0.f, 0.f, 0.f, 0.f};

    // ======================= Phase 1: QKV (2 tiles) ========================
    {
        _Float16       (*xT)[264] = (_Float16 (*)[264])smem;
        __hip_bfloat16 (*vst)[40] = (__hip_bfloat16 (*)[40])smem;

        #pragma unroll 1
        for (int s = 0; s < 2; ++s) {
            const int t  = idx * 2 + s;
            const int b  = (t & 7) >> 1;
            const int n0 = (((t >> 3) << 1) | (t & 1)) * 32;

            // stage x[256c][32n] -> xT[n][c] f16 (1024 threads, 1 slot each)
            {
                const float* xb = x + (size_t)b * CCH * N_PIX;
                const int c2 = (tid >> 3) * 2;
                const int n4 = (tid & 7) * 4;
                const float4 r0 = *(const float4*)(xb + (size_t)c2       * N_PIX + n0 + n4);
                const float4 r1 = *(const float4*)(xb + (size_t)(c2 + 1) * N_PIX + n0 + n4);
                const float a[4] = {r0.x, r0.y, r0.z, r0.w};
                const float c[4] = {r1.x, r1.y, r1.z, r1.w};
                #pragma unroll
                for (int i = 0; i < 4; ++i)
                    *(f16x2*)(&xT[n4 + i][c2]) = (f16x2){(_Float16)a[i], (_Float16)c[i]};
            }
            __syncthreads();

            f32x4 acc[2][2];
            #pragma unroll
            for (int j = 0; j < 2; ++j) { acc[j][0] = fz; acc[j][1] = fz; }

            if (wid < 10) {
                const _Float16* wpw = Wp + ((size_t)(wid * 2) * 8 * 64 + lane) * 8;
                #pragma unroll
                for (int ks = 0; ks < 8; ++ks) {
                    const f16x8 a0 = *(const f16x8*)(wpw + (size_t)(0 * 8 + ks) * 512);
                    const f16x8 a1 = *(const f16x8*)(wpw + (size_t)(1 * 8 + ks) * 512);
                    #pragma unroll
                    for (int nf = 0; nf < 2; ++nf) {
                        const f16x8 bfr = *(const f16x8*)(&xT[nf * 16 + L15][ks * 32 + quad * 8]);
                        acc[0][nf] = __builtin_amdgcn_mfma_f32_16x16x32_f16(a0, bfr, acc[0][nf], 0, 0, 0);
                        acc[1][nf] = __builtin_amdgcn_mfma_f32_16x16x32_f16(a1, bfr, acc[1][nf], 0, 0, 0);
                    }
                }
                // q/k epilogue (global, no LDS)
                #pragma unroll
                for (int j = 0; j < 2; ++j) {
                    const int m0 = (wid * 2 + j) * 16;
                    if (m0 < 32) {
                        const int mr = m0 + quad * 4;
                        #pragma unroll
                        for (int nf = 0; nf < 2; ++nf) {
                            const int n = n0 + nf * 16 + L15;
                            f16x4 h;
                            #pragma unroll
                            for (int r = 0; r < 4; ++r) h[r] = (_Float16)(acc[j][nf][r] + bq[mr + r] * LOG2E);
                            *(f16x4*)(qo + ((size_t)b * N_PIX + n) * DQK + mr) = h;
                        }
                    } else if (m0 < 64) {
                        const int mr = m0 - 32 + quad * 4;
                        #pragma unroll
                        for (int nf = 0; nf < 2; ++nf) {
                            const int n = n0 + nf * 16 + L15;
                            f16x4 h;
                            #pragma unroll
                            for (int r = 0; r < 4; ++r) h[r] = (_Float16)(acc[j][nf][r] + bk[mr + r]);
                            *(f16x4*)(ko + ((size_t)b * N_PIX + n) * DQK + mr) = h;
                        }
                    }
                }
            }
            __syncthreads();   // xT dead; vst aliases it

            if (wid < 10) {
                #pragma unroll
                for (int j = 0; j < 2; ++j) {
                    const int m0 = (wid * 2 + j) * 16;
                    if (m0 >= 64) {
                        const int c = m0 - 64 + quad * 4;
                        #pragma unroll
                        for (int nf = 0; nf < 2; ++nf) {
                            const int np = nf * 16 + L15;
                            #pragma unroll
                            for (int r = 0; r < 4; ++r)
                                vst[c + r][np] = __float2bfloat16(acc[j][nf][r] + bv[c + r]);
                        }
                    }
                }
            }
            __syncthreads();

            // packed store: 1024 threads, 1 slot each
            {
                __hip_bfloat16* vpb = vpk + (size_t)b * 2048 * 512 + (size_t)((n0 >> 5) * 16) * 512;
                const int cg16 = tid >> 6;
                const int ln   = tid & 63;
                const int qd   = ln >> 4;
                const int l15  = ln & 15;
                const bf16x8 val = *(const bf16x8*)(&vst[cg16 * 16 + l15][qd * 8]);
                *(bf16x8*)(vpb + ((size_t)cg16 * 64 + ln) * 8) = val;
            }
            __syncthreads();   // vst dead before next tile / phase 2
        }
    }

    // ===================== Grid barrier (device atomics) ===================
    __threadfence();          // release this block's q/k/Vp writes
    __syncthreads();
    if (tid == 0) {
        atomicAdd(cnt, 1u);
        while (atomicAdd(cnt, 0u) < 256u) __builtin_amdgcn_s_sleep(2);
    }
    __syncthreads();
    __threadfence();          // acquire other blocks' writes

    // ========================= Phase 2: attention ==========================
    __hip_bfloat16 (*Ps)[8][4][16][8] = (__hip_bfloat16 (*)[8][4][16][8])smem;  // [2][8][4][16][8]
    float          (*lsum)[4][16]     = (float (*)[4][16])(smem + 16384);       // [4][4][16]

    const int b  = (idx & 7) >> 1;
    const int n0 = (((idx >> 3) << 1) | (idx & 1)) * 64;
    const bool is_pv = (wid < 8);

    // ---- PV-wave state (wid 0..7)
    const int cg = wid & 7;
    const __hip_bfloat16* vb = vpk + (size_t)b * 2048 * 512;
    const int voff0 = lane * 8 + cg * 2 * 512;
    f32x4 oacc[4][2];
    #pragma unroll
    for (int qq = 0; qq < 4; ++qq) { oacc[qq][0] = fz; oacc[qq][1] = fz; }
    bf16x8 vA[2][2], vB[2][2];

    // ---- S-wave state (wid 8..15): skt = wid&3, h = (wid>>2)&1
    const int skt = wid & 3;
    const int h   = (wid >> 2) & 1;
    const int g0  = 4 * h + (skt >> 1);
    const int g1  = g0 + 2;
    const int s8  = (skt & 1) * 2 + (quad >> 1);
    const int e4  = (quad & 1) * 4;
    const _Float16* kbp = ko + (size_t)b * N_PIX * DQK;
    const int koff = (skt * 16 + L15) * DQK + quad * 8;
    f16x8 aq0{}, aq1{}, kA{}, kB{};
    float psum0 = 0.f, psum1 = 0.f;

    // ---- prologue
    if (is_pv) {
        #pragma unroll
        for (int kk = 0; kk < 2; ++kk)
            #pragma unroll
            for (int cf = 0; cf < 2; ++cf) {
                vA[kk][cf] = *(const bf16x8*)(vb +         voff0 + kk * 8192 + cf * 512);
                vB[kk][cf] = *(const bf16x8*)(vb + 16384 + voff0 + kk * 8192 + cf * 512);
            }
    } else {
        const _Float16* qbase = qo + ((size_t)b * N_PIX + n0 + L15) * DQK + quad * 8;
        aq0 = *(const f16x8*)(qbase + (size_t)((2 * h + 0) * 16) * DQK);
        aq1 = *(const f16x8*)(qbase + (size_t)((2 * h + 1) * 16) * DQK);
        const f16x8 k00 = *(const f16x8*)(kbp + koff);
        kA = *(const f16x8*)(kbp + (size_t)1 * 64 * DQK + koff);
        kB = *(const f16x8*)(kbp + (size_t)2 * 64 * DQK + koff);
        const f32x4 s0 = __builtin_amdgcn_mfma_f32_16x16x32_f16(k00, aq0, fz, 0, 0, 0);
        const f32x4 s1 = __builtin_amdgcn_mfma_f32_16x16x32_f16(k00, aq1, fz, 0, 0, 0);
        const float a0 = exp2f(s0[0]), a1 = exp2f(s0[1]);
        const float a2 = exp2f(s0[2]), a3 = exp2f(s0[3]);
        psum0 += (a0 + a1) + (a2 + a3);
        uint2 w0; w0.x = cvt_pk_bf16(a0, a1); w0.y = cvt_pk_bf16(a2, a3);
        *(uint2*)(&Ps[0][g0][s8][L15][e4]) = w0;
        const float b0 = exp2f(s1[0]), b1 = exp2f(s1[1]);
        const float b2 = exp2f(s1[2]), b3 = exp2f(s1[3]);
        psum1 += (b0 + b1) + (b2 + b3);
        uint2 w1; w1.x = cvt_pk_bf16(b0, b1); w1.y = cvt_pk_bf16(b2, b3);
        *(uint2*)(&Ps[0][g1][s8][L15][e4]) = w1;
    }
    barrier_lds();

    // ---- main loop: 64 bodies, x2 unrolled (P(J) lives in buf J&1)
    for (int it = 0; it < 64; it += 2) {
        if (is_pv) { PV_BODY(it, vA) } else { S_BODY(it, kA, true) }
        barrier_lds();
        if (is_pv) { PV_BODY(it + 1, vB) } else { S_BODY(it + 1, kB, it < 62) }
        barrier_lds();
    }

    // ---- epilogue: S waves publish row-sums, PV waves normalize + store
    if (!is_pv) {
        psum0 += __shfl_xor(psum0, 16, 64);
        psum0 += __shfl_xor(psum0, 32, 64);
        psum1 += __shfl_xor(psum1, 16, 64);
        psum1 += __shfl_xor(psum1, 32, 64);
        if (quad == 0) {
            lsum[2 * h + 0][skt][L15] = psum0;
            lsum[2 * h + 1][skt][L15] = psum1;
        }
    }
    __syncthreads();

    if (is_pv) {
        float* ob = out + (size_t)b * CCH * N_PIX;
        #pragma unroll
        for (int qq = 0; qq < 4; ++qq) {
            float inv_l[4];
            #pragma unroll
            for (int r = 0; r < 4; ++r) {
                const int q = quad * 4 + r;
                inv_l[r] = 1.f / (lsum[qq][0][q] + lsum[qq][1][q] +
                                  lsum[qq][2][q] + lsum[qq][3][q]);
            }
            #pragma unroll
            for (int cf = 0; cf < 2; ++cf) {
                const int c = cg * 32 + cf * 16 + L15;
                f32x4 o;
                #pragma unroll
                for (int r = 0; r < 4; ++r) o[r] = oacc[qq][cf][r] * inv_l[r];
                *(f32x4*)(ob + (size_t)c * N_PIX + n0 + qq * 16 + quad * 4) = o;
            }
        }
    }
}

// ---------------------------------------------------------------------------
extern "C" void kernel_launch(void* const* d_in, const int* in_sizes, int n_in,
                              void* d_out, int out_size, void* d_ws, size_t ws_size,
                              hipStream_t stream) {
    (void)in_sizes; (void)n_in; (void)out_size; (void)ws_size;
    const float* x  = (const float*)d_in[0];
    const float* Wq = (const float*)d_in[1];
    const float* bq = (const float*)d_in[2];
    const float* Wk = (const float*)d_in[3];
    const float* bk = (const float*)d_in[4];
    const float* Wv = (const float*)d_in[5];
    const float* bv = (const float*)d_in[6];

    // workspace: q 1MB | k 1MB | Vp 8MB | Wp 160KB | barrier counter 4B
    _Float16* qb = (_Float16*)d_ws;
    _Float16* kb = qb + (size_t)4 * N_PIX * DQK;
    __hip_bfloat16* vpk = (__hip_bfloat16*)(kb + (size_t)4 * N_PIX * DQK);
    _Float16* wp = (_Float16*)(vpk + (size_t)4 * 2048 * 512);
    unsigned* cnt = (unsigned*)(wp + (size_t)160 * 64 * 8);
    float* outp = (float*)d_out;

    wpack_kernel<<<40, 256, 0, stream>>>(Wq, Wk, Wv, wp, cnt);
    fused_kernel<<<256, 1024, 0, stream>>>(x, wp, bq, bk, bv, qb, kb, vpk, outp, cnt);
}

// Round 10
// 264.144 us; speedup vs baseline: 2.0640x; 2.0640x over previous
//
#include <hip/hip_runtime.h>
#include <hip/hip_bf16.h>

// B=4, C=256, N=HW=4096, Dqk=32.
// Round 18: R17's fusion test was poisoned by lb(1024,8) -> compiler clamped
// VGPR to 32 (demand ~96) -> 677MB scratch spill, 489us. But it QUANTIFIED
// the boundary cost: REST = 56us @2 launches vs 84us @3 launches = ~28us per
// kernel boundary (consistent across both). R18 = R17 with the ONLY change
// being __launch_bounds__(1024) (16 waves/CU -> 128-VGPR cap >= ~100 demand,
// no spill). Predicted: fused ~58-66us, total ~112-122us.
// Structure: wpack (zeroes grid-barrier counter, poison-safe) + fused kernel
// [Phase 1 = R14-style qkv, 2 x 32-px tiles/block; threadfence+atomicAdd grid
// barrier; Phase 2 = R15 attn (best measured, 52.1us standalone)].
// Carried: wave-specialized attn, K-dedup, conflict-free 16B-slot P layout,
// x2 unroll, SGPR-base addressing, &63 wrap prefetch, packed-Vp, S^T trick,
// LDS-only barrier, XCD swizzle, packed-W, no-max softmax.

#define N_PIX 4096
#define DQK   32
#define CCH   256
#define LOG2E 1.44269504088896f

typedef __attribute__((ext_vector_type(8))) _Float16 f16x8;
typedef __attribute__((ext_vector_type(4))) _Float16 f16x4;
typedef __attribute__((ext_vector_type(2))) _Float16 f16x2;
typedef __attribute__((ext_vector_type(8))) short    bf16x8;
typedef __attribute__((ext_vector_type(4))) short    bf16x4;
typedef __attribute__((ext_vector_type(4))) float    f32x4;

// LDS-only block barrier: waits lgkmcnt(0) but leaves vmcnt untouched.
__device__ inline void barrier_lds() {
    asm volatile("" ::: "memory");
    __builtin_amdgcn_s_waitcnt(0xc07f);   // vmcnt=63, expcnt=7, lgkmcnt=0
    __builtin_amdgcn_s_barrier();
    asm volatile("" ::: "memory");
}

// pack two f32 -> two bf16 in one instruction (RNE)
__device__ inline unsigned cvt_pk_bf16(float lo, float hi) {
    unsigned r;
    asm("v_cvt_pk_bf16_f32 %0, %1, %2" : "=v"(r) : "v"(lo), "v"(hi));
    return r;
}

// ---------------------------------------------------------------------------
// Kernel 0: pack Wq|Wk|Wv -> f16 A-fragments (LOG2E folded into Wq).
// Block 0 also zeroes the grid-barrier counter (re-poison-safe: runs every
// iteration, stream-ordered before the fused kernel).
// ---------------------------------------------------------------------------
__global__ __launch_bounds__(256) void wpack_kernel(
    const float* __restrict__ Wq, const float* __restrict__ Wk,
    const float* __restrict__ Wv, _Float16* __restrict__ Wp,
    unsigned* __restrict__ cnt)
{
    if (blockIdx.x == 0 && threadIdx.x == 0) atomicExch(cnt, 0u);

    const int tid   = threadIdx.x;
    const int wflat = blockIdx.x * 4 + (tid >> 6);   // 0..159
    const int lane  = tid & 63;
    const int L15   = lane & 15;
    const int quad  = lane >> 4;
    const int mt    = wflat >> 3;
    const int ks    = wflat & 7;
    const int m0    = mt * 16;

    const float* Wsrc; int row; float scale = 1.f;
    if (m0 < 32)      { Wsrc = Wq; row = m0 + L15;      scale = LOG2E; }
    else if (m0 < 64) { Wsrc = Wk; row = m0 - 32 + L15; }
    else              { Wsrc = Wv; row = m0 - 64 + L15; }

    const float* p = Wsrc + (size_t)row * 256 + ks * 32 + quad * 8;
    f16x8 h;
    #pragma unroll
    for (int j = 0; j < 8; ++j) h[j] = (_Float16)(p[j] * scale);
    *(f16x8*)(Wp + ((size_t)wflat * 64 + lane) * 8) = h;
}

// ---------------------------------------------------------------------------
// Fused kernel: Phase 1 = QKV (2 x 32-px tiles per block), grid barrier,
// Phase 2 = attention (R15 structure). Grid 256 (XCD-swizzled), 1024 thr.
// ---------------------------------------------------------------------------

#define PV_BODY(J, VR)                                                            \
  {                                                                               \
    const int buf_ = (J) & 1;                                                     \
    _Pragma("unroll")                                                             \
    for (int qq_ = 0; qq_ < 4; ++qq_) {                                           \
      _Pragma("unroll")                                                           \
      for (int kk_ = 0; kk_ < 2; ++kk_) {                                         \
        const bf16x8 ap_ = *(const bf16x8*)(&Ps[buf_][qq_ * 2 + kk_][quad][L15][0]); \
        oacc[qq_][0] = __builtin_amdgcn_mfma_f32_16x16x32_bf16(                   \
            ap_, VR[kk_][0], oacc[qq_][0], 0, 0, 0);                              \
        oacc[qq_][1] = __builtin_amdgcn_mfma_f32_16x16x32_bf16(                   \
            ap_, VR[kk_][1], oacc[qq_][1], 0, 0, 0);                              \
      }                                                                           \
    }                                                                             \
    const __hip_bfloat16* vt_ = vb + (size_t)(((J) + 2) & 63) * 16384;            \
    _Pragma("unroll")                                                             \
    for (int kk_ = 0; kk_ < 2; ++kk_)                                             \
      _Pragma("unroll")                                                           \
      for (int cf_ = 0; cf_ < 2; ++cf_)                                           \
        VR[kk_][cf_] = *(const bf16x8*)(vt_ + voff0 + kk_ * 8192 + cf_ * 512);    \
  }

// S body J (R15 K-dedup): computes S(J+1) for tiles (2h,skt),(2h+1,skt) from
// KR = K(J+1), writes P(J+1) to buf (J&1)^1, prefetches K(J+3) into KR.
#define S_BODY(J, KR, DO_S)                                                       \
  {                                                                               \
    if (DO_S) {                                                                   \
      const int bufw_ = ((J) & 1) ^ 1;                                            \
      const f32x4 s0_ = __builtin_amdgcn_mfma_f32_16x16x32_f16(KR, aq0, fz, 0, 0, 0); \
      const f32x4 s1_ = __builtin_amdgcn_mfma_f32_16x16x32_f16(KR, aq1, fz, 0, 0, 0); \
      const _Float16* kp_ = kbp + (size_t)(((J) + 3) & 63) * (64 * DQK);          \
      KR = *(const f16x8*)(kp_ + koff);                                           \
      const float a0_ = exp2f(s0_[0]), a1_ = exp2f(s0_[1]);                       \
      const float a2_ = exp2f(s0_[2]), a3_ = exp2f(s0_[3]);                       \
      psum0 += (a0_ + a1_) + (a2_ + a3_);                                         \
      uint2 w0_; w0_.x = cvt_pk_bf16(a0_, a1_); w0_.y = cvt_pk_bf16(a2_, a3_);    \
      *(uint2*)(&Ps[bufw_][g0][s8][L15][e4]) = w0_;                               \
      const float b0_ = exp2f(s1_[0]), b1_ = exp2f(s1_[1]);                       \
      const float b2_ = exp2f(s1_[2]), b3_ = exp2f(s1_[3]);                       \
      psum1 += (b0_ + b1_) + (b2_ + b3_);                                         \
      uint2 w1_; w1_.x = cvt_pk_bf16(b0_, b1_); w1_.y = cvt_pk_bf16(b2_, b3_);    \
      *(uint2*)(&Ps[bufw_][g1][s8][L15][e4]) = w1_;                               \
    }                                                                             \
  }

__global__ __launch_bounds__(1024) void fused_kernel(
    const float* __restrict__ x, const _Float16* __restrict__ Wp,
    const float* __restrict__ bq, const float* __restrict__ bk,
    const float* __restrict__ bv,
    _Float16* __restrict__ qo, _Float16* __restrict__ ko,
    __hip_bfloat16* __restrict__ vpk,
    float* __restrict__ out, unsigned* __restrict__ cnt)
{
    __shared__ alignas(16) unsigned char smem[20480];

    const int idx  = blockIdx.x;
    const int tid  = threadIdx.x;
    const int wid  = tid >> 6;
    const int lane = tid & 63;
    const int L15  = lane & 15;
    const int quad = lane >> 4;
    const f32x4 fz = {0.f, 0.f, 0.f, 0.f};

    // ======================= Phase 1: QKV (2 tiles) ========================
    {
        _Float16       (*xT)[264] = (_Float16 (*)[264])smem;
        __hip_bfloat16 (*vst)[40] = (__hip_bfloat16 (*)[40])smem;

        #pragma unroll 1
        for (int s = 0; s < 2; ++s) {
            const int t  = idx * 2 + s;
            const int b  = (t & 7) >> 1;
            const int n0 = (((t >> 3) << 1) | (t & 1)) * 32;

            // stage x[256c][32n] -> xT[n][c] f16 (1024 threads, 1 slot each)
            {
                const float* xb = x + (size_t)b * CCH * N_PIX;
                const int c2 = (tid >> 3) * 2;
                const int n4 = (tid & 7) * 4;
                const float4 r0 = *(const float4*)(xb + (size_t)c2       * N_PIX + n0 + n4);
                const float4 r1 = *(const float4*)(xb + (size_t)(c2 + 1) * N_PIX + n0 + n4);
                const float a[4] = {r0.x, r0.y, r0.z, r0.w};
                const float c[4] = {r1.x, r1.y, r1.z, r1.w};
                #pragma unroll
                for (int i = 0; i < 4; ++i)
                    *(f16x2*)(&xT[n4 + i][c2]) = (f16x2){(_Float16)a[i], (_Float16)c[i]};
            }
            __syncthreads();

            f32x4 acc[2][2];
            #pragma unroll
            for (int j = 0; j < 2; ++j) { acc[j][0] = fz; acc[j][1] = fz; }

            if (wid < 10) {
                const _Float16* wpw = Wp + ((size_t)(wid * 2) * 8 * 64 + lane) * 8;
                #pragma unroll
                for (int ks = 0; ks < 8; ++ks) {
                    const f16x8 a0 = *(const f16x8*)(wpw + (size_t)(0 * 8 + ks) * 512);
                    const f16x8 a1 = *(const f16x8*)(wpw + (size_t)(1 * 8 + ks) * 512);
                    #pragma unroll
                    for (int nf = 0; nf < 2; ++nf) {
                        const f16x8 bfr = *(const f16x8*)(&xT[nf * 16 + L15][ks * 32 + quad * 8]);
                        acc[0][nf] = __builtin_amdgcn_mfma_f32_16x16x32_f16(a0, bfr, acc[0][nf], 0, 0, 0);
                        acc[1][nf] = __builtin_amdgcn_mfma_f32_16x16x32_f16(a1, bfr, acc[1][nf], 0, 0, 0);
                    }
                }
                // q/k epilogue (global, no LDS)
                #pragma unroll
                for (int j = 0; j < 2; ++j) {
                    const int m0 = (wid * 2 + j) * 16;
                    if (m0 < 32) {
                        const int mr = m0 + quad * 4;
                        #pragma unroll
                        for (int nf = 0; nf < 2; ++nf) {
                            const int n = n0 + nf * 16 + L15;
                            f16x4 h;
                            #pragma unroll
                            for (int r = 0; r < 4; ++r) h[r] = (_Float16)(acc[j][nf][r] + bq[mr + r] * LOG2E);
                            *(f16x4*)(qo + ((size_t)b * N_PIX + n) * DQK + mr) = h;
                        }
                    } else if (m0 < 64) {
                        const int mr = m0 - 32 + quad * 4;
                        #pragma unroll
                        for (int nf = 0; nf < 2; ++nf) {
                            const int n = n0 + nf * 16 + L15;
                            f16x4 h;
                            #pragma unroll
                            for (int r = 0; r < 4; ++r) h[r] = (_Float16)(acc[j][nf][r] + bk[mr + r]);
                            *(f16x4*)(ko + ((size_t)b * N_PIX + n) * DQK + mr) = h;
                        }
                    }
                }
            }
            __syncthreads();   // xT dead; vst aliases it

            if (wid < 10) {
                #pragma unroll
                for (int j = 0; j < 2; ++j) {
                    const int m0 = (wid * 2 + j) * 16;
                    if (m0 >= 64) {
                        const int c = m0 - 64 + quad * 4;
                        #pragma unroll
                        for (int nf = 0; nf < 2; ++nf) {
                            const int np = nf * 16 + L15;
                            #pragma unroll
                            for (int r = 0; r < 4; ++r)
                                vst[c + r][np] = __float2bfloat16(acc[j][nf][r] + bv[c + r]);
                        }
                    }
                }
            }
            __syncthreads();

            // packed store: 1024 threads, 1 slot each
            {
                __hip_bfloat16* vpb = vpk + (size_t)b * 2048 * 512 + (size_t)((n0 >> 5) * 16) * 512;
                const int cg16 = tid >> 6;
                const int ln   = tid & 63;
                const int qd   = ln >> 4;
                const int l15  = ln & 15;
                const bf16x8 val = *(const bf16x8*)(&vst[cg16 * 16 + l15][qd * 8]);
                *(bf16x8*)(vpb + ((size_t)cg16 * 64 + ln) * 8) = val;
            }
            __syncthreads();   // vst dead before next tile / phase 2
        }
    }

    // ===================== Grid barrier (device atomics) ===================
    __threadfence();          // release this block's q/k/Vp writes
    __syncthreads();
    if (tid == 0) {
        atomicAdd(cnt, 1u);
        while (atomicAdd(cnt, 0u) < 256u) __builtin_amdgcn_s_sleep(2);
    }
    __syncthreads();
    __threadfence();          // acquire other blocks' writes

    // ========================= Phase 2: attention ==========================
    __hip_bfloat16 (*Ps)[8][4][16][8] = (__hip_bfloat16 (*)[8][4][16][8])smem;  // [2][8][4][16][8]
    float          (*lsum)[4][16]     = (float (*)[4][16])(smem + 16384);       // [4][4][16]

    const int b  = (idx & 7) >> 1;
    const int n0 = (((idx >> 3) << 1) | (idx & 1)) * 64;
    const bool is_pv = (wid < 8);

    // ---- PV-wave state (wid 0..7)
    const int cg = wid & 7;
    const __hip_bfloat16* vb = vpk + (size_t)b * 2048 * 512;
    const int voff0 = lane * 8 + cg * 2 * 512;
    f32x4 oacc[4][2];
    #pragma unroll
    for (int qq = 0; qq < 4; ++qq) { oacc[qq][0] = fz; oacc[qq][1] = fz; }
    bf16x8 vA[2][2], vB[2][2];

    // ---- S-wave state (wid 8..15): skt = wid&3, h = (wid>>2)&1
    const int skt = wid & 3;
    const int h   = (wid >> 2) & 1;
    const int g0  = 4 * h + (skt >> 1);
    const int g1  = g0 + 2;
    const int s8  = (skt & 1) * 2 + (quad >> 1);
    const int e4  = (quad & 1) * 4;
    const _Float16* kbp = ko + (size_t)b * N_PIX * DQK;
    const int koff = (skt * 16 + L15) * DQK + quad * 8;
    f16x8 aq0{}, aq1{}, kA{}, kB{};
    float psum0 = 0.f, psum1 = 0.f;

    // ---- prologue
    if (is_pv) {
        #pragma unroll
        for (int kk = 0; kk < 2; ++kk)
            #pragma unroll
            for (int cf = 0; cf < 2; ++cf) {
                vA[kk][cf] = *(const bf16x8*)(vb +         voff0 + kk * 8192 + cf * 512);
                vB[kk][cf] = *(const bf16x8*)(vb + 16384 + voff0 + kk * 8192 + cf * 512);
            }
    } else {
        const _Float16* qbase = qo + ((size_t)b * N_PIX + n0 + L15) * DQK + quad * 8;
        aq0 = *(const f16x8*)(qbase + (size_t)((2 * h + 0) * 16) * DQK);
        aq1 = *(const f16x8*)(qbase + (size_t)((2 * h + 1) * 16) * DQK);
        const f16x8 k00 = *(const f16x8*)(kbp + koff);
        kA = *(const f16x8*)(kbp + (size_t)1 * 64 * DQK + koff);
        kB = *(const f16x8*)(kbp + (size_t)2 * 64 * DQK + koff);
        const f32x4 s0 = __builtin_amdgcn_mfma_f32_16x16x32_f16(k00, aq0, fz, 0, 0, 0);
        const f32x4 s1 = __builtin_amdgcn_mfma_f32_16x16x32_f16(k00, aq1, fz, 0, 0, 0);
        const float a0 = exp2f(s0[0]), a1 = exp2f(s0[1]);
        const float a2 = exp2f(s0[2]), a3 = exp2f(s0[3]);
        psum0 += (a0 + a1) + (a2 + a3);
        uint2 w0; w0.x = cvt_pk_bf16(a0, a1); w0.y = cvt_pk_bf16(a2, a3);
        *(uint2*)(&Ps[0][g0][s8][L15][e4]) = w0;
        const float b0 = exp2f(s1[0]), b1 = exp2f(s1[1]);
        const float b2 = exp2f(s1[2]), b3 = exp2f(s1[3]);
        psum1 += (b0 + b1) + (b2 + b3);
        uint2 w1; w1.x = cvt_pk_bf16(b0, b1); w1.y = cvt_pk_bf16(b2, b3);
        *(uint2*)(&Ps[0][g1][s8][L15][e4]) = w1;
    }
    barrier_lds();

    // ---- main loop: 64 bodies, x2 unrolled (P(J) lives in buf J&1)
    for (int it = 0; it < 64; it += 2) {
        if (is_pv) { PV_BODY(it, vA) } else { S_BODY(it, kA, true) }
        barrier_lds();
        if (is_pv) { PV_BODY(it + 1, vB) } else { S_BODY(it + 1, kB, it < 62) }
        barrier_lds();
    }

    // ---- epilogue: S waves publish row-sums, PV waves normalize + store
    if (!is_pv) {
        psum0 += __shfl_xor(psum0, 16, 64);
        psum0 += __shfl_xor(psum0, 32, 64);
        psum1 += __shfl_xor(psum1, 16, 64);
        psum1 += __shfl_xor(psum1, 32, 64);
        if (quad == 0) {
            lsum[2 * h + 0][skt][L15] = psum0;
            lsum[2 * h + 1][skt][L15] = psum1;
        }
    }
    __syncthreads();

    if (is_pv) {
        float* ob = out + (size_t)b * CCH * N_PIX;
        #pragma unroll
        for (int qq = 0; qq < 4; ++qq) {
            float inv_l[4];
            #pragma unroll
            for (int r = 0; r < 4; ++r) {
                const int q = quad * 4 + r;
                inv_l[r] = 1.f / (lsum[qq][0][q] + lsum[qq][1][q] +
                                  lsum[qq][2][q] + lsum[qq][3][q]);
            }
            #pragma unroll
            for (int cf = 0; cf < 2; ++cf) {
                const int c = cg * 32 + cf * 16 + L15;
                f32x4 o;
                #pragma unroll
                for (int r = 0; r < 4; ++r) o[r] = oacc[qq][cf][r] * inv_l[r];
                *(f32x4*)(ob + (size_t)c * N_PIX + n0 + qq * 16 + quad * 4) = o;
            }
        }
    }
}

// ---------------------------------------------------------------------------
extern "C" void kernel_launch(void* const* d_in, const int* in_sizes, int n_in,
                              void* d_out, int out_size, void* d_ws, size_t ws_size,
                              hipStream_t stream) {
    (void)in_sizes; (void)n_in; (void)out_size; (void)ws_size;
    const float* x  = (const float*)d_in[0];
    const float* Wq = (const float*)d_in[1];
    const float* bq = (const float*)d_in[2];
    const float* Wk = (const float*)d_in[3];
    const float* bk = (const float*)d_in[4];
    const float* Wv = (const float*)d_in[5];
    const float* bv = (const float*)d_in[6];

    // workspace: q 1MB | k 1MB | Vp 8MB | Wp 160KB | barrier counter 4B
    _Float16* qb = (_Float16*)d_ws;
    _Float16* kb = qb + (size_t)4 * N_PIX * DQK;
    __hip_bfloat16* vpk = (__hip_bfloat16*)(kb + (size_t)4 * N_PIX * DQK);
    _Float16* wp = (_Float16*)(vpk + (size_t)4 * 2048 * 512);
    unsigned* cnt = (unsigned*)(wp + (size_t)160 * 64 * 8);
    float* outp = (float*)d_out;

    wpack_kernel<<<40, 256, 0, stream>>>(Wq, Wk, Wv, wp, cnt);
    fused_kernel<<<256, 1024, 0, stream>>>(x, wp, bq, bk, bv, qb, kb, vpk, outp, cnt);
}

// Round 11
// 263.347 us; speedup vs baseline: 2.0702x; 1.0030x over previous
//
#include <hip/hip_runtime.h>
#include <hip/hip_bf16.h>

// B=4, C=256, N=HW=4096, Dqk=32.
// Round 19: R18's fused kernel ran 199us = 3.8x the phase sum with counters
// an exact scaled fingerprint of the standalone kernels (Mfma 8.3 = 28*52/199)
// and Occupancy UP (46 vs 37) -> diagnosis: VGPR 64 + LDS 20KB lets the
// dispatcher pack 2 blocks/CU (launching behind wpack's 40 resident blocks),
// leaving other CUs empty; per-CU serialization (the established attn bound)
// doubles on packed CUs and the grid barrier syncs everyone to the stragglers.
// Fix (one line): pad static __shared__ to 84KB -> 2 blocks can't fit in
// 160KB/CU -> hardware forces 1 block/CU; grid 256 = #CUs, all co-resident.
// Predicted fused ~60-75us, total ~115-135us.
// Structure: wpack (zeroes grid-barrier counter, poison-safe) + fused kernel
// [Phase 1 = qkv, 2 x 32-px tiles/block; threadfence+atomicAdd grid barrier;
// Phase 2 = R15 attn]. Carried: wave-specialized attn, K-dedup, conflict-free
// 16B-slot P layout, x2 unroll, SGPR-base addressing, &63 wrap prefetch,
// packed-Vp, S^T trick, LDS-only barrier, XCD swizzle, packed-W, no-max SM.

#define N_PIX 4096
#define DQK   32
#define CCH   256
#define LOG2E 1.44269504088896f

typedef __attribute__((ext_vector_type(8))) _Float16 f16x8;
typedef __attribute__((ext_vector_type(4))) _Float16 f16x4;
typedef __attribute__((ext_vector_type(2))) _Float16 f16x2;
typedef __attribute__((ext_vector_type(8))) short    bf16x8;
typedef __attribute__((ext_vector_type(4))) short    bf16x4;
typedef __attribute__((ext_vector_type(4))) float    f32x4;

// LDS-only block barrier: waits lgkmcnt(0) but leaves vmcnt untouched.
__device__ inline void barrier_lds() {
    asm volatile("" ::: "memory");
    __builtin_amdgcn_s_waitcnt(0xc07f);   // vmcnt=63, expcnt=7, lgkmcnt=0
    __builtin_amdgcn_s_barrier();
    asm volatile("" ::: "memory");
}

// pack two f32 -> two bf16 in one instruction (RNE)
__device__ inline unsigned cvt_pk_bf16(float lo, float hi) {
    unsigned r;
    asm("v_cvt_pk_bf16_f32 %0, %1, %2" : "=v"(r) : "v"(lo), "v"(hi));
    return r;
}

// ---------------------------------------------------------------------------
// Kernel 0: pack Wq|Wk|Wv -> f16 A-fragments (LOG2E folded into Wq).
// Block 0 also zeroes the grid-barrier counter (re-poison-safe: runs every
// iteration, stream-ordered before the fused kernel).
// ---------------------------------------------------------------------------
__global__ __launch_bounds__(256) void wpack_kernel(
    const float* __restrict__ Wq, const float* __restrict__ Wk,
    const float* __restrict__ Wv, _Float16* __restrict__ Wp,
    unsigned* __restrict__ cnt)
{
    if (blockIdx.x == 0 && threadIdx.x == 0) atomicExch(cnt, 0u);

    const int tid   = threadIdx.x;
    const int wflat = blockIdx.x * 4 + (tid >> 6);   // 0..159
    const int lane  = tid & 63;
    const int L15   = lane & 15;
    const int quad  = lane >> 4;
    const int mt    = wflat >> 3;
    const int ks    = wflat & 7;
    const int m0    = mt * 16;

    const float* Wsrc; int row; float scale = 1.f;
    if (m0 < 32)      { Wsrc = Wq; row = m0 + L15;      scale = LOG2E; }
    else if (m0 < 64) { Wsrc = Wk; row = m0 - 32 + L15; }
    else              { Wsrc = Wv; row = m0 - 64 + L15; }

    const float* p = Wsrc + (size_t)row * 256 + ks * 32 + quad * 8;
    f16x8 h;
    #pragma unroll
    for (int j = 0; j < 8; ++j) h[j] = (_Float16)(p[j] * scale);
    *(f16x8*)(Wp + ((size_t)wflat * 64 + lane) * 8) = h;
}

// ---------------------------------------------------------------------------
// Fused kernel: Phase 1 = QKV (2 x 32-px tiles per block), grid barrier,
// Phase 2 = attention (R15 structure). Grid 256 (XCD-swizzled), 1024 thr.
// Static LDS padded to 84KB so two blocks cannot share a CU (160KB/CU limit).
// ---------------------------------------------------------------------------

#define PV_BODY(J, VR)                                                            \
  {                                                                               \
    const int buf_ = (J) & 1;                                                     \
    _Pragma("unroll")                                                             \
    for (int qq_ = 0; qq_ < 4; ++qq_) {                                           \
      _Pragma("unroll")                                                           \
      for (int kk_ = 0; kk_ < 2; ++kk_) {                                         \
        const bf16x8 ap_ = *(const bf16x8*)(&Ps[buf_][qq_ * 2 + kk_][quad][L15][0]); \
        oacc[qq_][0] = __builtin_amdgcn_mfma_f32_16x16x32_bf16(                   \
            ap_, VR[kk_][0], oacc[qq_][0], 0, 0, 0);                              \
        oacc[qq_][1] = __builtin_amdgcn_mfma_f32_16x16x32_bf16(                   \
            ap_, VR[kk_][1], oacc[qq_][1], 0, 0, 0);                              \
      }                                                                           \
    }                                                                             \
    const __hip_bfloat16* vt_ = vb + (size_t)(((J) + 2) & 63) * 16384;            \
    _Pragma("unroll")                                                             \
    for (int kk_ = 0; kk_ < 2; ++kk_)                                             \
      _Pragma("unroll")                                                           \
      for (int cf_ = 0; cf_ < 2; ++cf_)                                           \
        VR[kk_][cf_] = *(const bf16x8*)(vt_ + voff0 + kk_ * 8192 + cf_ * 512);    \
  }

// S body J (R15 K-dedup): computes S(J+1) for tiles (2h,skt),(2h+1,skt) from
// KR = K(J+1), writes P(J+1) to buf (J&1)^1, prefetches K(J+3) into KR.
#define S_BODY(J, KR, DO_S)                                                       \
  {                                                                               \
    if (DO_S) {                                                                   \
      const int bufw_ = ((J) & 1) ^ 1;                                            \
      const f32x4 s0_ = __builtin_amdgcn_mfma_f32_16x16x32_f16(KR, aq0, fz, 0, 0, 0); \
      const f32x4 s1_ = __builtin_amdgcn_mfma_f32_16x16x32_f16(KR, aq1, fz, 0, 0, 0); \
      const _Float16* kp_ = kbp + (size_t)(((J) + 3) & 63) * (64 * DQK);          \
      KR = *(const f16x8*)(kp_ + koff);                                           \
      const float a0_ = exp2f(s0_[0]), a1_ = exp2f(s0_[1]);                       \
      const float a2_ = exp2f(s0_[2]), a3_ = exp2f(s0_[3]);                       \
      psum0 += (a0_ + a1_) + (a2_ + a3_);                                         \
      uint2 w0_; w0_.x = cvt_pk_bf16(a0_, a1_); w0_.y = cvt_pk_bf16(a2_, a3_);    \
      *(uint2*)(&Ps[bufw_][g0][s8][L15][e4]) = w0_;                               \
      const float b0_ = exp2f(s1_[0]), b1_ = exp2f(s1_[1]);                       \
      const float b2_ = exp2f(s1_[2]), b3_ = exp2f(s1_[3]);                       \
      psum1 += (b0_ + b1_) + (b2_ + b3_);                                         \
      uint2 w1_; w1_.x = cvt_pk_bf16(b0_, b1_); w1_.y = cvt_pk_bf16(b2_, b3_);    \
      *(uint2*)(&Ps[bufw_][g1][s8][L15][e4]) = w1_;                               \
    }                                                                             \
  }

__global__ __launch_bounds__(1024) void fused_kernel(
    const float* __restrict__ x, const _Float16* __restrict__ Wp,
    const float* __restrict__ bq, const float* __restrict__ bk,
    const float* __restrict__ bv,
    _Float16* __restrict__ qo, _Float16* __restrict__ ko,
    __hip_bfloat16* __restrict__ vpk,
    float* __restrict__ out, unsigned* __restrict__ cnt)
{
    // 84KB: only 20.5KB used; the rest blocks a second workgroup from the CU.
    __shared__ alignas(16) unsigned char smem[86016];

    const int idx  = blockIdx.x;
    const int tid  = threadIdx.x;
    const int wid  = tid >> 6;
    const int lane = tid & 63;
    const int L15  = lane & 15;
    const int quad = lane >> 4;
    const f32x4 fz = {0.f, 0.f, 0.f, 0.f};

    // ======================= Phase 1: QKV (2 tiles) ========================
    {
        _Float16       (*xT)[264] = (_Float16 (*)[264])smem;
        __hip_bfloat16 (*vst)[40] = (__hip_bfloat16 (*)[40])smem;

        #pragma unroll 1
        for (int s = 0; s < 2; ++s) {
            const int t  = idx * 2 + s;
            const int b  = (t & 7) >> 1;
            const int n0 = (((t >> 3) << 1) | (t & 1)) * 32;

            // stage x[256c][32n] -> xT[n][c] f16 (1024 threads, 1 slot each)
            {
                const float* xb = x + (size_t)b * CCH * N_PIX;
                const int c2 = (tid >> 3) * 2;
                const int n4 = (tid & 7) * 4;
                const float4 r0 = *(const float4*)(xb + (size_t)c2       * N_PIX + n0 + n4);
                const float4 r1 = *(const float4*)(xb + (size_t)(c2 + 1) * N_PIX + n0 + n4);
                const float a[4] = {r0.x, r0.y, r0.z, r0.w};
                const float c[4] = {r1.x, r1.y, r1.z, r1.w};
                #pragma unroll
                for (int i = 0; i < 4; ++i)
                    *(f16x2*)(&xT[n4 + i][c2]) = (f16x2){(_Float16)a[i], (_Float16)c[i]};
            }
            __syncthreads();

            f32x4 acc[2][2];
            #pragma unroll
            for (int j = 0; j < 2; ++j) { acc[j][0] = fz; acc[j][1] = fz; }

            if (wid < 10) {
                const _Float16* wpw = Wp + ((size_t)(wid * 2) * 8 * 64 + lane) * 8;
                #pragma unroll
                for (int ks = 0; ks < 8; ++ks) {
                    const f16x8 a0 = *(const f16x8*)(wpw + (size_t)(0 * 8 + ks) * 512);
                    const f16x8 a1 = *(const f16x8*)(wpw + (size_t)(1 * 8 + ks) * 512);
                    #pragma unroll
                    for (int nf = 0; nf < 2; ++nf) {
                        const f16x8 bfr = *(const f16x8*)(&xT[nf * 16 + L15][ks * 32 + quad * 8]);
                        acc[0][nf] = __builtin_amdgcn_mfma_f32_16x16x32_f16(a0, bfr, acc[0][nf], 0, 0, 0);
                        acc[1][nf] = __builtin_amdgcn_mfma_f32_16x16x32_f16(a1, bfr, acc[1][nf], 0, 0, 0);
                    }
                }
                // q/k epilogue (global, no LDS)
                #pragma unroll
                for (int j = 0; j < 2; ++j) {
                    const int m0 = (wid * 2 + j) * 16;
                    if (m0 < 32) {
                        const int mr = m0 + quad * 4;
                        #pragma unroll
                        for (int nf = 0; nf < 2; ++nf) {
                            const int n = n0 + nf * 16 + L15;
                            f16x4 h;
                            #pragma unroll
                            for (int r = 0; r < 4; ++r) h[r] = (_Float16)(acc[j][nf][r] + bq[mr + r] * LOG2E);
                            *(f16x4*)(qo + ((size_t)b * N_PIX + n) * DQK + mr) = h;
                        }
                    } else if (m0 < 64) {
                        const int mr = m0 - 32 + quad * 4;
                        #pragma unroll
                        for (int nf = 0; nf < 2; ++nf) {
                            const int n = n0 + nf * 16 + L15;
                            f16x4 h;
                            #pragma unroll
                            for (int r = 0; r < 4; ++r) h[r] = (_Float16)(acc[j][nf][r] + bk[mr + r]);
                            *(f16x4*)(ko + ((size_t)b * N_PIX + n) * DQK + mr) = h;
                        }
                    }
                }
            }
            __syncthreads();   // xT dead; vst aliases it

            if (wid < 10) {
                #pragma unroll
                for (int j = 0; j < 2; ++j) {
                    const int m0 = (wid * 2 + j) * 16;
                    if (m0 >= 64) {
                        const int c = m0 - 64 + quad * 4;
                        #pragma unroll
                        for (int nf = 0; nf < 2; ++nf) {
                            const int np = nf * 16 + L15;
                            #pragma unroll
                            for (int r = 0; r < 4; ++r)
                                vst[c + r][np] = __float2bfloat16(acc[j][nf][r] + bv[c + r]);
                        }
                    }
                }
            }
            __syncthreads();

            // packed store: 1024 threads, 1 slot each
            {
                __hip_bfloat16* vpb = vpk + (size_t)b * 2048 * 512 + (size_t)((n0 >> 5) * 16) * 512;
                const int cg16 = tid >> 6;
                const int ln   = tid & 63;
                const int qd   = ln >> 4;
                const int l15  = ln & 15;
                const bf16x8 val = *(const bf16x8*)(&vst[cg16 * 16 + l15][qd * 8]);
                *(bf16x8*)(vpb + ((size_t)cg16 * 64 + ln) * 8) = val;
            }
            __syncthreads();   // vst dead before next tile / phase 2
        }
    }

    // ===================== Grid barrier (device atomics) ===================
    __threadfence();          // release this block's q/k/Vp writes
    __syncthreads();
    if (tid == 0) {
        atomicAdd(cnt, 1u);
        while (atomicAdd(cnt, 0u) < 256u) __builtin_amdgcn_s_sleep(2);
    }
    __syncthreads();
    __threadfence();          // acquire other blocks' writes

    // ========================= Phase 2: attention ==========================
    __hip_bfloat16 (*Ps)[8][4][16][8] = (__hip_bfloat16 (*)[8][4][16][8])smem;  // [2][8][4][16][8]
    float          (*lsum)[4][16]     = (float (*)[4][16])(smem + 16384);       // [4][4][16]

    const int b  = (idx & 7) >> 1;
    const int n0 = (((idx >> 3) << 1) | (idx & 1)) * 64;
    const bool is_pv = (wid < 8);

    // ---- PV-wave state (wid 0..7)
    const int cg = wid & 7;
    const __hip_bfloat16* vb = vpk + (size_t)b * 2048 * 512;
    const int voff0 = lane * 8 + cg * 2 * 512;
    f32x4 oacc[4][2];
    #pragma unroll
    for (int qq = 0; qq < 4; ++qq) { oacc[qq][0] = fz; oacc[qq][1] = fz; }
    bf16x8 vA[2][2], vB[2][2];

    // ---- S-wave state (wid 8..15): skt = wid&3, h = (wid>>2)&1
    const int skt = wid & 3;
    const int h   = (wid >> 2) & 1;
    const int g0  = 4 * h + (skt >> 1);
    const int g1  = g0 + 2;
    const int s8  = (skt & 1) * 2 + (quad >> 1);
    const int e4  = (quad & 1) * 4;
    const _Float16* kbp = ko + (size_t)b * N_PIX * DQK;
    const int koff = (skt * 16 + L15) * DQK + quad * 8;
    f16x8 aq0{}, aq1{}, kA{}, kB{};
    float psum0 = 0.f, psum1 = 0.f;

    // ---- prologue
    if (is_pv) {
        #pragma unroll
        for (int kk = 0; kk < 2; ++kk)
            #pragma unroll
            for (int cf = 0; cf < 2; ++cf) {
                vA[kk][cf] = *(const bf16x8*)(vb +         voff0 + kk * 8192 + cf * 512);
                vB[kk][cf] = *(const bf16x8*)(vb + 16384 + voff0 + kk * 8192 + cf * 512);
            }
    } else {
        const _Float16* qbase = qo + ((size_t)b * N_PIX + n0 + L15) * DQK + quad * 8;
        aq0 = *(const f16x8*)(qbase + (size_t)((2 * h + 0) * 16) * DQK);
        aq1 = *(const f16x8*)(qbase + (size_t)((2 * h + 1) * 16) * DQK);
        const f16x8 k00 = *(const f16x8*)(kbp + koff);
        kA = *(const f16x8*)(kbp + (size_t)1 * 64 * DQK + koff);
        kB = *(const f16x8*)(kbp + (size_t)2 * 64 * DQK + koff);
        const f32x4 s0 = __builtin_amdgcn_mfma_f32_16x16x32_f16(k00, aq0, fz, 0, 0, 0);
        const f32x4 s1 = __builtin_amdgcn_mfma_f32_16x16x32_f16(k00, aq1, fz, 0, 0, 0);
        const float a0 = exp2f(s0[0]), a1 = exp2f(s0[1]);
        const float a2 = exp2f(s0[2]), a3 = exp2f(s0[3]);
        psum0 += (a0 + a1) + (a2 + a3);
        uint2 w0; w0.x = cvt_pk_bf16(a0, a1); w0.y = cvt_pk_bf16(a2, a3);
        *(uint2*)(&Ps[0][g0][s8][L15][e4]) = w0;
        const float b0 = exp2f(s1[0]), b1 = exp2f(s1[1]);
        const float b2 = exp2f(s1[2]), b3 = exp2f(s1[3]);
        psum1 += (b0 + b1) + (b2 + b3);
        uint2 w1; w1.x = cvt_pk_bf16(b0, b1); w1.y = cvt_pk_bf16(b2, b3);
        *(uint2*)(&Ps[0][g1][s8][L15][e4]) = w1;
    }
    barrier_lds();

    // ---- main loop: 64 bodies, x2 unrolled (P(J) lives in buf J&1)
    for (int it = 0; it < 64; it += 2) {
        if (is_pv) { PV_BODY(it, vA) } else { S_BODY(it, kA, true) }
        barrier_lds();
        if (is_pv) { PV_BODY(it + 1, vB) } else { S_BODY(it + 1, kB, it < 62) }
        barrier_lds();
    }

    // ---- epilogue: S waves publish row-sums, PV waves normalize + store
    if (!is_pv) {
        psum0 += __shfl_xor(psum0, 16, 64);
        psum0 += __shfl_xor(psum0, 32, 64);
        psum1 += __shfl_xor(psum1, 16, 64);
        psum1 += __shfl_xor(psum1, 32, 64);
        if (quad == 0) {
            lsum[2 * h + 0][skt][L15] = psum0;
            lsum[2 * h + 1][skt][L15] = psum1;
        }
    }
    __syncthreads();

    if (is_pv) {
        float* ob = out + (size_t)b * CCH * N_PIX;
        #pragma unroll
        for (int qq = 0; qq < 4; ++qq) {
            float inv_l[4];
            #pragma unroll
            for (int r = 0; r < 4; ++r) {
                const int q = quad * 4 + r;
                inv_l[r] = 1.f / (lsum[qq][0][q] + lsum[qq][1][q] +
                                  lsum[qq][2][q] + lsum[qq][3][q]);
            }
            #pragma unroll
            for (int cf = 0; cf < 2; ++cf) {
                const int c = cg * 32 + cf * 16 + L15;
                f32x4 o;
                #pragma unroll
                for (int r = 0; r < 4; ++r) o[r] = oacc[qq][cf][r] * inv_l[r];
                *(f32x4*)(ob + (size_t)c * N_PIX + n0 + qq * 16 + quad * 4) = o;
            }
        }
    }
}

// ---------------------------------------------------------------------------
extern "C" void kernel_launch(void* const* d_in, const int* in_sizes, int n_in,
                              void* d_out, int out_size, void* d_ws, size_t ws_size,
                              hipStream_t stream) {
    (void)in_sizes; (void)n_in; (void)out_size; (void)ws_size;
    const float* x  = (const float*)d_in[0];
    const float* Wq = (const float*)d_in[1];
    const float* bq = (const float*)d_in[2];
    const float* Wk = (const float*)d_in[3];
    const float* bk = (const float*)d_in[4];
    const float* Wv = (const float*)d_in[5];
    const float* bv = (const float*)d_in[6];

    // workspace: q 1MB | k 1MB | Vp 8MB | Wp 160KB | barrier counter 4B
    _Float16* qb = (_Float16*)d_ws;
    _Float16* kb = qb + (size_t)4 * N_PIX * DQK;
    __hip_bfloat16* vpk = (__hip_bfloat16*)(kb + (size_t)4 * N_PIX * DQK);
    _Float16* wp = (_Float16*)(vpk + (size_t)4 * 2048 * 512);
    unsigned* cnt = (unsigned*)(wp + (size_t)160 * 64 * 8);
    float* outp = (float*)d_out;

    wpack_kernel<<<40, 256, 0, stream>>>(Wq, Wk, Wv, wp, cnt);
    fused_kernel<<<256, 1024, 0, stream>>>(x, wp, bq, bk, bv, qb, kb, vpk, outp, cnt);
}

// Round 12
// 132.963 us; speedup vs baseline: 4.1003x; 1.9806x over previous
//
#include <hip/hip_runtime.h>
#include <hip/hip_bf16.h>

// B=4, C=256, N=HW=4096, Dqk=32.
// Round 20: REVERT to R15 (best measured: 135.6us total, attn 52.1us).
// Fusion line (R17-R19) abandoned: fused kernel runs 199us = 3.8x phase sum
// with uniformly scaled counters at 1 block/CU (packing theory falsified by
// R19's 84KB LDS pad); mechanism unidentified from source. REST accounting
// settled by R17/R18: qkv ~20-27us, wpack+harness-restores+gaps ~56-60us
// (harness-fixed). Controllable floor = attn 52 + qkv ~23 ~ 75us -> total
// ~135us = R15's measurement. attn itself is pinned at ~1960 cyc/body across
// six falsified structural theories (VALU, barrier domains, vector BW,
// pipeline depth, byte totals, wave count) -- empirical floor for this
// structure. This file is the R15 source verbatim.
// Carried: wave-specialized attn (8 PV + 8 S waves), K-dedup (one K-frag
// feeds 2 q-tile MFMAs), conflict-free 16B-slot P layout, x2 unroll named
// reg sets, SGPR-base addressing, &63 wrap prefetch, packed-Vp, S^T trick,
// LDS-only barrier, XCD swizzle, packed-W qkv (640-thr, W-dedup), no-max SM.

#define N_PIX 4096
#define DQK   32
#define CCH   256
#define LOG2E 1.44269504088896f

typedef __attribute__((ext_vector_type(8))) _Float16 f16x8;
typedef __attribute__((ext_vector_type(4))) _Float16 f16x4;
typedef __attribute__((ext_vector_type(2))) _Float16 f16x2;
typedef __attribute__((ext_vector_type(8))) short    bf16x8;
typedef __attribute__((ext_vector_type(4))) short    bf16x4;
typedef __attribute__((ext_vector_type(4))) float    f32x4;

// LDS-only block barrier: waits lgkmcnt(0) but leaves vmcnt untouched.
__device__ inline void barrier_lds() {
    asm volatile("" ::: "memory");
    __builtin_amdgcn_s_waitcnt(0xc07f);   // vmcnt=63, expcnt=7, lgkmcnt=0
    __builtin_amdgcn_s_barrier();
    asm volatile("" ::: "memory");
}

// pack two f32 -> two bf16 in one instruction (RNE)
__device__ inline unsigned cvt_pk_bf16(float lo, float hi) {
    unsigned r;
    asm("v_cvt_pk_bf16_f32 %0, %1, %2" : "=v"(r) : "v"(lo), "v"(hi));
    return r;
}

// ---------------------------------------------------------------------------
// Kernel 0: pack Wq|Wk|Wv -> f16 A-fragments, lane-ordered (LOG2E folded into Wq).
// ---------------------------------------------------------------------------
__global__ __launch_bounds__(256) void wpack_kernel(
    const float* __restrict__ Wq, const float* __restrict__ Wk,
    const float* __restrict__ Wv, _Float16* __restrict__ Wp)
{
    const int tid   = threadIdx.x;
    const int wflat = blockIdx.x * 4 + (tid >> 6);   // 0..159
    const int lane  = tid & 63;
    const int L15   = lane & 15;
    const int quad  = lane >> 4;
    const int mt    = wflat >> 3;
    const int ks    = wflat & 7;
    const int m0    = mt * 16;

    const float* Wsrc; int row; float scale = 1.f;
    if (m0 < 32)      { Wsrc = Wq; row = m0 + L15;      scale = LOG2E; }
    else if (m0 < 64) { Wsrc = Wk; row = m0 - 32 + L15; }
    else              { Wsrc = Wv; row = m0 - 64 + L15; }

    const float* p = Wsrc + (size_t)row * 256 + ks * 32 + quad * 8;
    f16x8 h;
    #pragma unroll
    for (int j = 0; j < 8; ++j) h[j] = (_Float16)(p[j] * scale);
    *(f16x8*)(Wp + ((size_t)wflat * 64 + lane) * 8) = h;
}

// ---------------------------------------------------------------------------
// Kernel 1: QKV projection, f16 MFMA, packed W. Grid 512, 640 thr = 10 waves,
// 32-pixel tiles. Wave wid owns m-tiles {2*wid, 2*wid+1}; A-frags held in
// registers per ks-step and reused across BOTH 16-pixel halves.
// V output goes through LDS transpose -> packed B-frag layout:
//   Vp[b][(n0>>5)*16 + cg16][lane(quad,L15)][j] = v[cg16*16+L15][n0 + quad*8+j]
// ---------------------------------------------------------------------------
__global__ __launch_bounds__(640, 5) void qkv_kernel(
    const float* __restrict__ x, const _Float16* __restrict__ Wp,
    const float* __restrict__ bq, const float* __restrict__ bk,
    const float* __restrict__ bv,
    _Float16* __restrict__ qo, _Float16* __restrict__ ko,
    __hip_bfloat16* __restrict__ vp)
{
    // shared: xT (32x264 f16 = 16.9KB) then reused as vst (256x40 bf16 = 20KB)
    __shared__ alignas(16) unsigned char shraw[256 * 40 * 2];
    _Float16       (*xT)[264] = (_Float16 (*)[264])shraw;
    __hip_bfloat16 (*vst)[40] = (__hip_bfloat16 (*)[40])shraw;

    const int idx = blockIdx.x;
    const int b   = (idx & 7) >> 1;
    const int n0  = (((idx >> 3) << 1) | (idx & 1)) * 32;
    const int tid = threadIdx.x;

    // stage x[256c][32n] -> xT[n][c] f16  (1024 slots over 640 threads)
    {
        const float* xb = x + (size_t)b * CCH * N_PIX;
        #pragma unroll
        for (int pass = 0; pass < 2; ++pass) {
            const int slot = pass * 640 + tid;
            if (slot < 1024) {
                const int c2 = (slot >> 3) * 2;
                const int n4 = (slot & 7) * 4;
                const float4 r0 = *(const float4*)(xb + (size_t)c2       * N_PIX + n0 + n4);
                const float4 r1 = *(const float4*)(xb + (size_t)(c2 + 1) * N_PIX + n0 + n4);
                const float a[4] = {r0.x, r0.y, r0.z, r0.w};
                const float c[4] = {r1.x, r1.y, r1.z, r1.w};
                #pragma unroll
                for (int i = 0; i < 4; ++i)
                    *(f16x2*)(&xT[n4 + i][c2]) = (f16x2){(_Float16)a[i], (_Float16)c[i]};
            }
        }
    }
    __syncthreads();

    const int lane = tid & 63;
    const int wid  = tid >> 6;   // 0..9, owns m-tiles {2wid, 2wid+1}
    const int L15  = lane & 15;
    const int quad = lane >> 4;

    const f32x4 fz = {0.f, 0.f, 0.f, 0.f};
    f32x4 acc[2][2];   // [j (m-tile)][nf (pixel half)]
    #pragma unroll
    for (int j = 0; j < 2; ++j) { acc[j][0] = fz; acc[j][1] = fz; }

    const _Float16* wpw = Wp + ((size_t)(wid * 2) * 8 * 64 + lane) * 8;

    #pragma unroll
    for (int ks = 0; ks < 8; ++ks) {
        const f16x8 a0 = *(const f16x8*)(wpw + (size_t)(0 * 8 + ks) * 512);
        const f16x8 a1 = *(const f16x8*)(wpw + (size_t)(1 * 8 + ks) * 512);
        #pragma unroll
        for (int nf = 0; nf < 2; ++nf) {
            const f16x8 bfr = *(const f16x8*)(&xT[nf * 16 + L15][ks * 32 + quad * 8]);
            acc[0][nf] = __builtin_amdgcn_mfma_f32_16x16x32_f16(a0, bfr, acc[0][nf], 0, 0, 0);
            acc[1][nf] = __builtin_amdgcn_mfma_f32_16x16x32_f16(a1, bfr, acc[1][nf], 0, 0, 0);
        }
    }

    // q/k epilogue (global, no LDS): C/D row = out-row (quad*4+r), col = pixel (L15)
    #pragma unroll
    for (int j = 0; j < 2; ++j) {
        const int m0 = (wid * 2 + j) * 16;
        if (m0 < 32) {
            const int mr = m0 + quad * 4;
            #pragma unroll
            for (int nf = 0; nf < 2; ++nf) {
                const int n = n0 + nf * 16 + L15;
                f16x4 h;
                #pragma unroll
                for (int r = 0; r < 4; ++r) h[r] = (_Float16)(acc[j][nf][r] + bq[mr + r] * LOG2E);
                *(f16x4*)(qo + ((size_t)b * N_PIX + n) * DQK + mr) = h;
            }
        } else if (m0 < 64) {
            const int mr = m0 - 32 + quad * 4;
            #pragma unroll
            for (int nf = 0; nf < 2; ++nf) {
                const int n = n0 + nf * 16 + L15;
                f16x4 h;
                #pragma unroll
                for (int r = 0; r < 4; ++r) h[r] = (_Float16)(acc[j][nf][r] + bk[mr + r]);
                *(f16x4*)(ko + ((size_t)b * N_PIX + n) * DQK + mr) = h;
            }
        }
    }

    __syncthreads();   // xT dead; vst aliases it

    // v -> LDS transpose buffer vst[ch][pix] (rows padded to 40 elems, 16B-aligned)
    #pragma unroll
    for (int j = 0; j < 2; ++j) {
        const int m0 = (wid * 2 + j) * 16;
        if (m0 >= 64) {
            const int c = m0 - 64 + quad * 4;
            #pragma unroll
            for (int nf = 0; nf < 2; ++nf) {
                const int np = nf * 16 + L15;
                #pragma unroll
                for (int r = 0; r < 4; ++r)
                    vst[c + r][np] = __float2bfloat16(acc[j][nf][r] + bv[c + r]);
            }
        }
    }
    __syncthreads();

    // packed store: slot (cg16, lane'=(qd,l15)) -> one b128 LDS read + one 16B store
    {
        __hip_bfloat16* vpb = vp + (size_t)b * 2048 * 512 + (size_t)((n0 >> 5) * 16) * 512;
        #pragma unroll
        for (int s = 0; s < 2; ++s) {
            const int slot = s * 640 + tid;   // 0..1279, use 0..1023
            if (slot < 1024) {
                const int cg16 = slot >> 6;
                const int ln   = slot & 63;
                const int qd   = ln >> 4;
                const int l15  = ln & 15;
                const bf16x8 val = *(const bf16x8*)(&vst[cg16 * 16 + l15][qd * 8]);
                *(bf16x8*)(vpb + ((size_t)cg16 * 64 + ln) * 8) = val;
            }
        }
    }
}

// ---------------------------------------------------------------------------
// Kernel 2: attention. Grid 256 (XCD-swizzled), 1024 threads = 16 waves,
// 64 q/block, 1 block/CU. Wave-specialized, 2-buffer P, barrier per body.
//   PV waves (wid 0..7): cg owns 32 ch x all 64 q (byte-optimal blocking).
//   S waves (wid 8..15): (skt = wid&3, h = (wid>>2)&1): k-tile skt for
//     q-tiles {2h, 2h+1}. ONE 1KB K-frag per body feeds 2 MFMAs (K-dedup).
// P layout: Ps[buf][g][kb8][L15][8e]; tile (sqt,kt) -> group g = sqt*2+(kt>>1),
// slot kb8 = (kt&1)*2+(quad>>1), elem (quad&1)*4. PV reads 1KB contiguous
// (0 conflicts), S uint2 writes 4/bank balanced.
// ---------------------------------------------------------------------------

#define PV_BODY(J, VR)                                                            \
  {                                                                               \
    const int buf_ = (J) & 1;                                                     \
    _Pragma("unroll")                                                             \
    for (int qq_ = 0; qq_ < 4; ++qq_) {                                           \
      _Pragma("unroll")                                                           \
      for (int kk_ = 0; kk_ < 2; ++kk_) {                                         \
        const bf16x8 ap_ = *(const bf16x8*)(&Ps[buf_][qq_ * 2 + kk_][quad][L15][0]); \
        oacc[qq_][0] = __builtin_amdgcn_mfma_f32_16x16x32_bf16(                   \
            ap_, VR[kk_][0], oacc[qq_][0], 0, 0, 0);                              \
        oacc[qq_][1] = __builtin_amdgcn_mfma_f32_16x16x32_bf16(                   \
            ap_, VR[kk_][1], oacc[qq_][1], 0, 0, 0);                              \
      }                                                                           \
    }                                                                             \
    const __hip_bfloat16* vt_ = vb + (size_t)(((J) + 2) & 63) * 16384;            \
    _Pragma("unroll")                                                             \
    for (int kk_ = 0; kk_ < 2; ++kk_)                                             \
      _Pragma("unroll")                                                           \
      for (int cf_ = 0; cf_ < 2; ++cf_)                                           \
        VR[kk_][cf_] = *(const bf16x8*)(vt_ + voff0 + kk_ * 8192 + cf_ * 512);    \
  }

// S body J: computes S(J+1) for tiles (2h,skt),(2h+1,skt) from KR = K(J+1),
// writes P(J+1) to buf (J&1)^1, prefetches K(J+3) into KR.
#define S_BODY(J, KR, DO_S)                                                       \
  {                                                                               \
    if (DO_S) {                                                                   \
      const int bufw_ = ((J) & 1) ^ 1;                                            \
      const f32x4 s0_ = __builtin_amdgcn_mfma_f32_16x16x32_f16(KR, aq0, fz, 0, 0, 0); \
      const f32x4 s1_ = __builtin_amdgcn_mfma_f32_16x16x32_f16(KR, aq1, fz, 0, 0, 0); \
      const _Float16* kp_ = kbp + (size_t)(((J) + 3) & 63) * (64 * DQK);          \
      KR = *(const f16x8*)(kp_ + koff);                                           \
      const float a0_ = exp2f(s0_[0]), a1_ = exp2f(s0_[1]);                       \
      const float a2_ = exp2f(s0_[2]), a3_ = exp2f(s0_[3]);                       \
      psum0 += (a0_ + a1_) + (a2_ + a3_);                                         \
      uint2 w0_; w0_.x = cvt_pk_bf16(a0_, a1_); w0_.y = cvt_pk_bf16(a2_, a3_);    \
      *(uint2*)(&Ps[bufw_][g0][s8][L15][e4]) = w0_;                               \
      const float b0_ = exp2f(s1_[0]), b1_ = exp2f(s1_[1]);                       \
      const float b2_ = exp2f(s1_[2]), b3_ = exp2f(s1_[3]);                       \
      psum1 += (b0_ + b1_) + (b2_ + b3_);                                         \
      uint2 w1_; w1_.x = cvt_pk_bf16(b0_, b1_); w1_.y = cvt_pk_bf16(b2_, b3_);    \
      *(uint2*)(&Ps[bufw_][g1][s8][L15][e4]) = w1_;                               \
    }                                                                             \
  }

__global__ __launch_bounds__(1024, 4) void attn_kernel(
    const _Float16* __restrict__ qg,        // [B][N][32], q pre-scaled by log2e
    const _Float16* __restrict__ kg,        // [B][N][32]
    const __hip_bfloat16* __restrict__ vp,  // packed: [B][2048 chunks][64][8]
    float* __restrict__ out)                // [B][C][N]
{
    __shared__ __hip_bfloat16 Ps[2][8][4][16][8];   // 16KB; [buf][g][kb8][L15][e]
    __shared__ float lsum[4][4][16];                // [sqt][kt][query]

    const int idx  = blockIdx.x;
    const int b    = (idx & 7) >> 1;
    const int n0   = (((idx >> 3) << 1) | (idx & 1)) * 64;
    const int tid  = threadIdx.x;
    const int wid  = tid >> 6;
    const int lane = tid & 63;
    const int L15  = lane & 15;
    const int quad = lane >> 4;
    const bool is_pv = (wid < 8);

    const f32x4 fz = {0.f, 0.f, 0.f, 0.f};

    // ---- PV-wave state (wid 0..7)
    const int cg = wid & 7;                        // 32-channel group
    const __hip_bfloat16* vb = vp + (size_t)b * 2048 * 512;
    const int voff0 = lane * 8 + cg * 2 * 512;     // + kk*8192 + cf*512
    f32x4 oacc[4][2];
    #pragma unroll
    for (int qq = 0; qq < 4; ++qq) { oacc[qq][0] = fz; oacc[qq][1] = fz; }
    bf16x8 vA[2][2], vB[2][2];

    // ---- S-wave state (wid 8..15): skt = wid&3 (k-tile), h = (wid>>2)&1
    //      tiles (sqt=2h, skt) and (sqt=2h+1, skt); ONE K-frag per body.
    const int skt = wid & 3;
    const int h   = (wid >> 2) & 1;
    const int g0  = 4 * h + (skt >> 1);            // group of tile (2h, skt)
    const int g1  = g0 + 2;                        // group of tile (2h+1, skt)
    const int s8  = (skt & 1) * 2 + (quad >> 1);   // kb8 slot within group
    const int e4  = (quad & 1) * 4;                // element offset
    const _Float16* kbp = kg + (size_t)b * N_PIX * DQK;
    const int koff = (skt * 16 + L15) * DQK + quad * 8;
    f16x8 aq0{}, aq1{}, kA{}, kB{};
    float psum0 = 0.f, psum1 = 0.f;

    // ---- prologue
    if (is_pv) {
        #pragma unroll
        for (int kk = 0; kk < 2; ++kk)
            #pragma unroll
            for (int cf = 0; cf < 2; ++cf) {
                vA[kk][cf] = *(const bf16x8*)(vb +                 voff0 + kk * 8192 + cf * 512);
                vB[kk][cf] = *(const bf16x8*)(vb + (size_t)16384 + voff0 + kk * 8192 + cf * 512);
            }
    } else {
        aq0 = *(const f16x8*)(qg + ((size_t)b * N_PIX + n0 + (2 * h + 0) * 16 + L15) * DQK + quad * 8);
        aq1 = *(const f16x8*)(qg + ((size_t)b * N_PIX + n0 + (2 * h + 1) * 16 + L15) * DQK + quad * 8);
        const f16x8 k00 = *(const f16x8*)(kbp + koff);
        kA = *(const f16x8*)(kbp + (size_t)1 * 64 * DQK + koff);
        kB = *(const f16x8*)(kbp + (size_t)2 * 64 * DQK + koff);
        const f32x4 s0 = __builtin_amdgcn_mfma_f32_16x16x32_f16(k00, aq0, fz, 0, 0, 0);
        const f32x4 s1 = __builtin_amdgcn_mfma_f32_16x16x32_f16(k00, aq1, fz, 0, 0, 0);
        const float a0 = exp2f(s0[0]), a1 = exp2f(s0[1]);
        const float a2 = exp2f(s0[2]), a3 = exp2f(s0[3]);
        psum0 += (a0 + a1) + (a2 + a3);
        uint2 w0; w0.x = cvt_pk_bf16(a0, a1); w0.y = cvt_pk_bf16(a2, a3);
        *(uint2*)(&Ps[0][g0][s8][L15][e4]) = w0;
        const float b0 = exp2f(s1[0]), b1 = exp2f(s1[1]);
        const float b2 = exp2f(s1[2]), b3 = exp2f(s1[3]);
        psum1 += (b0 + b1) + (b2 + b3);
        uint2 w1; w1.x = cvt_pk_bf16(b0, b1); w1.y = cvt_pk_bf16(b2, b3);
        *(uint2*)(&Ps[0][g1][s8][L15][e4]) = w1;
    }
    barrier_lds();

    // ---- main loop: 64 bodies, x2 unrolled (P(J) lives in buf J&1)
    for (int it = 0; it < 64; it += 2) {
        if (is_pv) { PV_BODY(it, vA) } else { S_BODY(it, kA, true) }
        barrier_lds();
        if (is_pv) { PV_BODY(it + 1, vB) } else { S_BODY(it + 1, kB, it < 62) }
        barrier_lds();
    }

    // ---- epilogue: S waves publish row-sums, PV waves normalize + store
    if (!is_pv) {
        psum0 += __shfl_xor(psum0, 16, 64);
        psum0 += __shfl_xor(psum0, 32, 64);
        psum1 += __shfl_xor(psum1, 16, 64);
        psum1 += __shfl_xor(psum1, 32, 64);
        if (quad == 0) {
            lsum[2 * h + 0][skt][L15] = psum0;
            lsum[2 * h + 1][skt][L15] = psum1;
        }
    }
    __syncthreads();

    if (is_pv) {
        float* ob = out + (size_t)b * CCH * N_PIX;
        #pragma unroll
        for (int qq = 0; qq < 4; ++qq) {
            float inv_l[4];
            #pragma unroll
            for (int r = 0; r < 4; ++r) {
                const int q = quad * 4 + r;
                inv_l[r] = 1.f / (lsum[qq][0][q] + lsum[qq][1][q] +
                                  lsum[qq][2][q] + lsum[qq][3][q]);
            }
            #pragma unroll
            for (int cf = 0; cf < 2; ++cf) {
                const int c = cg * 32 + cf * 16 + L15;
                f32x4 o;
                #pragma unroll
                for (int r = 0; r < 4; ++r) o[r] = oacc[qq][cf][r] * inv_l[r];
                *(f32x4*)(ob + (size_t)c * N_PIX + n0 + qq * 16 + quad * 4) = o;
            }
        }
    }
}

// ---------------------------------------------------------------------------
extern "C" void kernel_launch(void* const* d_in, const int* in_sizes, int n_in,
                              void* d_out, int out_size, void* d_ws, size_t ws_size,
                              hipStream_t stream) {
    (void)in_sizes; (void)n_in; (void)out_size; (void)ws_size;
    const float* x  = (const float*)d_in[0];
    const float* Wq = (const float*)d_in[1];
    const float* bq = (const float*)d_in[2];
    const float* Wk = (const float*)d_in[3];
    const float* bk = (const float*)d_in[4];
    const float* Wv = (const float*)d_in[5];
    const float* bv = (const float*)d_in[6];

    // workspace: q 1MB | k 1MB | Vp 8MB | Wp 160KB
    _Float16* qb = (_Float16*)d_ws;
    _Float16* kb = qb + (size_t)4 * N_PIX * DQK;
    __hip_bfloat16* vpk = (__hip_bfloat16*)(kb + (size_t)4 * N_PIX * DQK);
    _Float16* wp = (_Float16*)(vpk + (size_t)4 * 2048 * 512);
    float* outp = (float*)d_out;

    wpack_kernel<<<40, 256, 0, stream>>>(Wq, Wk, Wv, wp);
    qkv_kernel<<<512, 640, 0, stream>>>(x, wp, bq, bk, bv, qb, kb, vpk);
    attn_kernel<<<256, 1024, 0, stream>>>(qb, kb, vpk, outp);
}